// Round 1
// baseline (1909.748 us; speedup 1.0000x reference)
//
#include <hip/hip_runtime.h>
#include <hip/hip_fp16.h>
#include <stdint.h>
#include <stddef.h>

// Problem constants
#define B_N   8
#define C_N   256
#define H_N   256
#define W_N   256
#define HW_N  65536
#define NSEL  6554        // int(HW*0.1)+1
#define NTOT  52432       // B*NSEL
#define NHALF 26216       // NTOT/2 (threefry counter halves)
#define LOSS_BLOCKS 2048

// ---- workspace layout (bytes, 256-aligned regions) ----
static constexpr size_t OFF_BND      = 0;          // f32[B*HW]          2,097,152
static constexpr size_t OFF_HIST_HI  = 2097152;    // u32[B*65536]       2,097,152  (zeroed)
static constexpr size_t OFF_HIST_LO  = 4194304;    // u32[B*65536]       2,097,152  (zeroed)
static constexpr size_t OFF_BUCKETA  = 6291456;    // u32[65536]           262,144  (zeroed)
static constexpr size_t OFF_RANKINFO = 6553600;    // u32[64]: b0,r0,b1,r1,cc0,cc1 (zeroed)
static constexpr size_t OFF_SELPOS   = 6553856;    // u16[B*HW]          1,048,576  (fill 0xFFFF)
static constexpr size_t OFF_MIN      = 7602432;    // u64[2]             (fill 0xFF)
static constexpr size_t OFF_THR      = 7602688;    // u32[32]: hb[8], r[8], Tkey[8], eqneed[8]
static constexpr size_t OFF_CNT      = 7602944;    // u32: cnt0[8], cnt1[8], ms@16
static constexpr size_t OFF_CENTERS  = 7603200;    // f32[128]
static constexpr size_t OFF_CAND     = 7603712;    // u64[2][512]
static constexpr size_t OFF_LIST0    = 7611904;    // u32[NTOT]
static constexpr size_t OFF_LIST1    = 7821824;    // u32[NTOT]
static constexpr size_t OFF_PARTIAL  = 8031744;    // f64[8192]
static constexpr size_t OFF_XG       = 8097280;    // f16[256*NTOT]     26,845,184
static constexpr size_t OFF_MASKED   = 34942464;   // f32[NTOT*64]      13,422,592 -> end 48,365,056

#define ZERO_WORDS   1114176   // HIST_HI..RANKINFO end
#define SELPOS_WORDS 262144

// ===================== init =====================
__global__ void k_init(char* ws){
  int i = blockIdx.x * 256 + threadIdx.x;
  if (i < ZERO_WORDS)   ((unsigned*)(ws + OFF_HIST_HI))[i] = 0u;
  if (i < SELPOS_WORDS) ((unsigned*)(ws + OFF_SELPOS))[i]  = 0xFFFFFFFFu;
  if (i < 4)            ((unsigned*)(ws + OFF_MIN))[i]     = 0xFFFFFFFFu;
}

// ===================== boundary map (f64 accumulation) =====================
// block=256 (4 waves = 4 rows), grid = B*H/4 = 512. Each thread: 4 pixels via float4.
__global__ __launch_bounds__(256) void k_bnd(const float* __restrict__ Fe, float* __restrict__ bnd){
  const int bid = blockIdx.x;
  const int b  = bid >> 6;
  const int h  = ((bid & 63) << 2) + (threadIdx.x >> 6);
  const int tx = threadIdx.x & 63;
  const int w  = tx << 2;
  const size_t base = (size_t)b * C_N * HW_N + (size_t)h * W_N + w;
  const int hn = (h < H_N - 1) ? (h + 1) : (H_N - 2);   // replicate: gy[255]=|Fe[255]-Fe[254]|
  const ptrdiff_t roff = (ptrdiff_t)(hn - h) * W_N;
  double a0 = 0.0, a1 = 0.0, a2 = 0.0, a3 = 0.0;
  for (int c = 0; c < C_N; ++c){
    const float* p = Fe + base + (size_t)c * HW_N;
    const float4 va = *(const float4*)p;
    const float4 vg = *(const float4*)(p + roff);
    const float nx = __shfl_down(va.x, 1);
    const float gx0 = fabsf(va.y - va.x);
    const float gx1 = fabsf(va.z - va.y);
    const float gx2 = fabsf(va.w - va.z);
    const float gx3 = (tx < 63) ? fabsf(nx - va.w) : gx2;  // replicate gx[255]=gx[254]
    a0 += (double)(gx0 + fabsf(vg.x - va.x));
    a1 += (double)(gx1 + fabsf(vg.y - va.y));
    a2 += (double)(gx2 + fabsf(vg.z - va.z));
    a3 += (double)(gx3 + fabsf(vg.w - va.w));
  }
  float4 o; o.x = (float)a0; o.y = (float)a1; o.z = (float)a2; o.w = (float)a3;
  *(float4*)(bnd + (size_t)b * HW_N + (size_t)h * W_N + w) = o;
}

// ===================== top-NSEL radix select =====================
__global__ void k_hist_hi(const float* __restrict__ bnd, unsigned* __restrict__ hist){
  int i = blockIdx.x * 256 + threadIdx.x;     // grid 2048
  int b = i >> 16;
  unsigned key = __float_as_uint(bnd[i]);     // bnd >= 0 -> uint order == float order
  atomicAdd(&hist[b * 65536 + (key >> 16)], 1u);
}

__global__ void k_thresh_hi(const unsigned* __restrict__ hist, unsigned* __restrict__ thr){
  __shared__ unsigned s[1024];
  int b = blockIdx.x, t = threadIdx.x;
  const unsigned* hb = hist + b * 65536;
  unsigned sum = 0;
  for (int k = 0; k < 64; ++k) sum += hb[t * 64 + k];
  s[t] = sum; __syncthreads();
  if (t == 0){
    unsigned cum = 0; int tc = 1023;
    for (; tc >= 0; --tc){ if (cum + s[tc] >= NSEL) break; cum += s[tc]; }
    unsigned hbkt = 0, r = 0, c2 = cum;
    for (int k = 63; k >= 0; --k){
      unsigned v = hb[tc * 64 + k];
      if (c2 + v >= NSEL){ hbkt = (unsigned)(tc * 64 + k); r = NSEL - c2; break; }
      c2 += v;
    }
    thr[b] = hbkt; thr[8 + b] = r;
  }
}

__global__ void k_hist_lo(const float* __restrict__ bnd, const unsigned* __restrict__ thr,
                          unsigned* __restrict__ histlo){
  int i = blockIdx.x * 256 + threadIdx.x;
  int b = i >> 16;
  unsigned key = __float_as_uint(bnd[i]);
  if ((key >> 16) == thr[b]) atomicAdd(&histlo[b * 65536 + (key & 0xFFFFu)], 1u);
}

__global__ void k_thresh_lo(const unsigned* __restrict__ histlo, unsigned* __restrict__ thr){
  __shared__ unsigned s[1024];
  int b = blockIdx.x, t = threadIdx.x;
  const unsigned* hb = histlo + b * 65536;
  unsigned sum = 0;
  for (int k = 0; k < 64; ++k) sum += hb[t * 64 + k];
  s[t] = sum; __syncthreads();
  if (t == 0){
    unsigned target = thr[8 + b];
    unsigned cum = 0; int tc = 1023;
    for (; tc >= 0; --tc){ if (cum + s[tc] >= target) break; cum += s[tc]; }
    unsigned lb = 0, eqneed = 0, c2 = cum;
    for (int k = 63; k >= 0; --k){
      unsigned v = hb[tc * 64 + k];
      if (c2 + v >= target){ lb = (unsigned)(tc * 64 + k); eqneed = target - c2; break; }
      c2 += v;
    }
    thr[16 + b] = (thr[b] << 16) | lb;   // full 32-bit threshold key
    thr[24 + b] = eqneed;                // # ties at T to take (index order, == top_k tie-break)
  }
}

// ordered compaction: selpos[b][p] = rank among selected (pixel order), 0xFFFF otherwise
__global__ void k_compact(const float* __restrict__ bnd, const unsigned* __restrict__ thr,
                          unsigned short* __restrict__ selpos){
  __shared__ unsigned sg[1024], se[1024];
  int b = blockIdx.x, t = threadIdx.x;
  unsigned T = thr[16 + b], need = thr[24 + b];
  const float* bb = bnd + (size_t)b * HW_N;
  int p0 = t * 64;
  unsigned ng = 0, ne = 0;
  for (int k = 0; k < 64; ++k){
    unsigned key = __float_as_uint(bb[p0 + k]);
    ng += (key > T); ne += (key == T);
  }
  sg[t] = ng; se[t] = ne; __syncthreads();
  if (t == 0){
    unsigned a = 0, e = 0;
    for (int i = 0; i < 1024; ++i){ unsigned x = sg[i], y = se[i]; sg[i] = a; se[i] = e; a += x; e += y; }
  }
  __syncthreads();
  unsigned g = sg[t], e = se[t];
  for (int k = 0; k < 64; ++k){
    int p = p0 + k;
    unsigned key = __float_as_uint(bb[p]);
    if (key > T){
      unsigned etk = e < need ? e : need;
      selpos[(size_t)b * HW_N + p] = (unsigned short)(g + etk);
      ++g;
    } else if (key == T){
      if (e < need) selpos[(size_t)b * HW_N + p] = (unsigned short)(g + e);
      ++e;
    }
  }
}

// ===================== coalesced gather Fe -> Xg[c][t] (fp16) =====================
__global__ void k_gather(const float* __restrict__ Fe, const unsigned short* __restrict__ selpos,
                         __half* __restrict__ Xg){
  const int b = blockIdx.z, c = blockIdx.y;
  const int p = blockIdx.x * 1024 + threadIdx.x * 4;
  const float4 v = *(const float4*)(Fe + ((size_t)(b * C_N + c)) * HW_N + p);
  const ushort4 s = *(const ushort4*)(selpos + (size_t)b * HW_N + p);
  __half* xc = Xg + (size_t)c * NTOT + (size_t)b * NSEL;
  if (s.x != 0xFFFFu) xc[s.x] = __float2half(v.x);
  if (s.y != 0xFFFFu) xc[s.y] = __float2half(v.y);
  if (s.z != 0xFFFFu) xc[s.z] = __float2half(v.z);
  if (s.w != 0xFFFFu) xc[s.w] = __float2half(v.w);
}

// ===================== projection MLP at selected points =====================
// block=256 (4 waves), 64 points/block. lane=point, wave=k/e chunk. f32 compute.
__global__ __launch_bounds__(256, 2) void k_mlp(const __half* __restrict__ Xg,
    const float* __restrict__ w1, const float* __restrict__ b1,
    const float* __restrict__ w2, const float* __restrict__ b2,
    float* __restrict__ masked){
  __shared__ float xs[64 * 129];   // x chunk [pt][128], reused as h [pt][128]
  const int t0 = blockIdx.x * 64;
  const int tid = threadIdx.x;
  const int wv = __builtin_amdgcn_readfirstlane(tid >> 6);
  const int pt = tid & 63;
  const int t = t0 + pt;

  float acc[32];
  #pragma unroll
  for (int kk = 0; kk < 32; ++kk) acc[kk] = b1[wv * 32 + kk];

  for (int half = 0; half < 2; ++half){
    for (int it = 0; it < 32; ++it){
      int idx = it * 256 + tid;
      int cl = idx >> 6, ptl = idx & 63;
      int tt = t0 + ptl;
      float v = 0.f;
      if (tt < NTOT) v = __half2float(Xg[(size_t)(half * 128 + cl) * NTOT + tt]);
      xs[ptl * 129 + cl] = v;
    }
    __syncthreads();
    for (int cc = 0; cc < 128; cc += 32){
      float xr[32];
      #pragma unroll
      for (int j = 0; j < 32; ++j) xr[j] = xs[pt * 129 + cc + j];
      #pragma unroll
      for (int kk = 0; kk < 32; ++kk){
        const float* wr = w1 + (size_t)(wv * 32 + kk) * 256 + half * 128 + cc;
        float a = acc[kk];
        #pragma unroll
        for (int j = 0; j < 32; ++j) a = fmaf(wr[j], xr[j], a);
        acc[kk] = a;
      }
    }
    __syncthreads();
  }
  // write h (relu) into xs, then second layer
  #pragma unroll
  for (int kk = 0; kk < 32; ++kk) xs[pt * 129 + wv * 32 + kk] = fmaxf(acc[kk], 0.f);
  __syncthreads();

  float o[16];
  #pragma unroll
  for (int ee = 0; ee < 16; ++ee) o[ee] = b2[wv * 16 + ee];
  for (int kc = 0; kc < 128; kc += 32){
    float hr[32];
    #pragma unroll
    for (int j = 0; j < 32; ++j) hr[j] = xs[pt * 129 + kc + j];
    #pragma unroll
    for (int ee = 0; ee < 16; ++ee){
      const float* wr = w2 + (size_t)(wv * 16 + ee) * 128 + kc;
      float a = o[ee];
      #pragma unroll
      for (int j = 0; j < 32; ++j) a = fmaf(wr[j], hr[j], a);
      o[ee] = a;
    }
  }
  if (t < NTOT){
    float4* mp = (float4*)(masked + (size_t)t * 64 + wv * 16);
    mp[0] = make_float4(o[0], o[1], o[2], o[3]);
    mp[1] = make_float4(o[4], o[5], o[6], o[7]);
    mp[2] = make_float4(o[8], o[9], o[10], o[11]);
    mp[3] = make_float4(o[12], o[13], o[14], o[15]);
  }
}

// ===================== threefry (jax.random.permutation(key(42), NTOT)[:2]) =====================
__device__ __forceinline__ unsigned rotl32(unsigned x, int d){ return (x << d) | (x >> (32 - d)); }

__device__ __forceinline__ void threefry(unsigned k0, unsigned k1, unsigned& x0, unsigned& x1){
  const unsigned ks2 = k0 ^ k1 ^ 0x1BD11BDAu;
  x0 += k0; x1 += k1;
#define TFR(r) { x0 += x1; x1 = rotl32(x1, r); x1 ^= x0; }
  TFR(13) TFR(15) TFR(26) TFR(6)  x0 += k1;  x1 += ks2 + 1u;
  TFR(17) TFR(29) TFR(16) TFR(24) x0 += ks2; x1 += k0 + 2u;
  TFR(13) TFR(15) TFR(26) TFR(6)  x0 += k0;  x1 += k1 + 3u;
  TFR(17) TFR(29) TFR(16) TFR(24) x0 += k1;  x1 += ks2 + 4u;
  TFR(13) TFR(15) TFR(26) TFR(6)  x0 += ks2; x1 += k0 + 5u;
#undef TFR
}

// key chain: key0=(0,42); split -> (key1, subA); split(key1) -> (_, subB)
__device__ __forceinline__ void get_subkeys(unsigned& a0, unsigned& a1, unsigned& b0, unsigned& b1){
  unsigned x0 = 0u, x1 = 2u; threefry(0u, 42u, x0, x1);   // pair (0,2)
  unsigned y0 = 1u, y1 = 3u; threefry(0u, 42u, y0, y1);   // pair (1,3)
  a0 = x1; a1 = y1;                                        // subkeyA = x1-lane outputs
  unsigned p0 = 0u, p1 = 2u; threefry(x0, y0, p0, p1);     // key1 = x0-lane outputs
  unsigned q0 = 1u, q1 = 3u; threefry(x0, y0, q0, q1);
  b0 = p1; b1 = q1;                                        // subkeyB
}

// round-1 key histogram (hi16) + round-2 stable argmin
__global__ void k_tf1(unsigned* __restrict__ bucketA, unsigned long long* __restrict__ minb){
  int q = blockIdx.x * 256 + threadIdx.x;
  if (q >= NHALF) return;
  unsigned a0, a1, b0, b1; get_subkeys(a0, a1, b0, b1);
  unsigned xa0 = (unsigned)q, xa1 = (unsigned)(q + NHALF); threefry(a0, a1, xa0, xa1);
  atomicAdd(&bucketA[xa0 >> 16], 1u);
  atomicAdd(&bucketA[xa1 >> 16], 1u);
  unsigned xb0 = (unsigned)q, xb1 = (unsigned)(q + NHALF); threefry(b0, b1, xb0, xb1);
  unsigned long long p0 = (((unsigned long long)xb0) << 32) | (unsigned)q;
  unsigned long long p1 = (((unsigned long long)xb1) << 32) | (unsigned)(q + NHALF);
  atomicMin(&minb[0], p0 < p1 ? p0 : p1);
}

__global__ void k_tf2(unsigned long long* __restrict__ minb){
  int q = blockIdx.x * 256 + threadIdx.x;
  if (q >= NHALF) return;
  unsigned a0, a1, b0, b1; get_subkeys(a0, a1, b0, b1);
  unsigned xb0 = (unsigned)q, xb1 = (unsigned)(q + NHALF); threefry(b0, b1, xb0, xb1);
  unsigned j0 = (unsigned)(minb[0] & 0xFFFFFFFFull);
  unsigned long long p0 = (((unsigned long long)xb0) << 32) | (unsigned)q;
  unsigned long long p1 = (((unsigned long long)xb1) << 32) | (unsigned)(q + NHALF);
  unsigned long long m = ~0ull;
  if ((unsigned)q != j0) m = p0;
  if ((unsigned)(q + NHALF) != j0 && p1 < m) m = p1;
  if (m != ~0ull) atomicMin(&minb[1], m);
}

// find buckets/ranks for target ranks j0, j1 in keysA order statistics
__global__ void k_rank(const unsigned long long* __restrict__ minb,
                       const unsigned* __restrict__ bucketA, unsigned* __restrict__ rankinfo){
  __shared__ unsigned s[1024];
  int t = threadIdx.x;
  unsigned sum = 0;
  for (int k = 0; k < 64; ++k) sum += bucketA[t * 64 + k];
  s[t] = sum; __syncthreads();
  if (t == 0){
    for (int which = 0; which < 2; ++which){
      unsigned target = (unsigned)(minb[which] & 0xFFFFFFFFull);
      unsigned cum = 0; int tc = 0;
      for (; tc < 1024; ++tc){ if (cum + s[tc] > target) break; cum += s[tc]; }
      unsigned bkt = 0, r = 0, c2 = cum;
      for (int k = 0; k < 64; ++k){
        unsigned v = bucketA[tc * 64 + k];
        if (c2 + v > target){ bkt = (unsigned)(tc * 64 + k); r = target - c2; break; }
        c2 += v;
      }
      rankinfo[which * 2 + 0] = bkt;
      rankinfo[which * 2 + 1] = r;
    }
  }
}

__global__ void k_cand(unsigned* __restrict__ rankinfo, unsigned long long* __restrict__ cand){
  int q = blockIdx.x * 256 + threadIdx.x;
  if (q >= NHALF) return;
  unsigned a0, a1, b0, b1; get_subkeys(a0, a1, b0, b1);
  unsigned xa0 = (unsigned)q, xa1 = (unsigned)(q + NHALF); threefry(a0, a1, xa0, xa1);
  unsigned keys[2] = { xa0, xa1 };
  unsigned pos[2]  = { (unsigned)q, (unsigned)(q + NHALF) };
  for (int l = 0; l < 2; ++l){
    unsigned long long pk = (((unsigned long long)keys[l]) << 32) | pos[l];
    if ((keys[l] >> 16) == rankinfo[0]){
      unsigned slot = atomicAdd(&rankinfo[4], 1u);
      if (slot < 512) cand[slot] = pk;
    }
    if ((keys[l] >> 16) == rankinfo[2]){
      unsigned slot = atomicAdd(&rankinfo[5], 1u);
      if (slot < 512) cand[512 + slot] = pk;
    }
  }
}

__global__ void k_pick(const unsigned* __restrict__ rankinfo, const unsigned long long* __restrict__ cand,
                       const float* __restrict__ masked, float* __restrict__ centers){
  __shared__ unsigned sel[2];
  int t = threadIdx.x;
  for (int which = 0; which < 2; ++which){
    unsigned n = rankinfo[4 + which]; if (n > 512) n = 512;
    unsigned r = rankinfo[which * 2 + 1];
    const unsigned long long* cd = cand + which * 512;
    if ((unsigned)t < n){
      unsigned long long me = cd[t];
      unsigned rank = 0;
      for (unsigned i = 0; i < n; ++i) rank += (cd[i] < me);
      if (rank == r) sel[which] = (unsigned)(me & 0xFFFFFFFFull);
    }
  }
  __syncthreads();
  if (t < 64){
    centers[t]      = masked[(size_t)sel[0] * 64 + t];
    centers[64 + t] = masked[(size_t)sel[1] * 64 + t];
  }
}

// ===================== labels + ordered per-cluster compaction =====================
__global__ void k_labels(const float* __restrict__ masked, const float* __restrict__ centers,
                         unsigned* __restrict__ list0, unsigned* __restrict__ list1,
                         unsigned* __restrict__ cnt){
  __shared__ float c0[64], c1[64];
  __shared__ unsigned s0[1024], s1[1024];
  int b = blockIdx.x, t = threadIdx.x;
  if (t < 64) c0[t] = centers[t];
  else if (t < 128) c1[t - 64] = centers[t];
  __syncthreads();
  unsigned bits = 0, n0 = 0, n1 = 0;
  int j0 = t * 7;
  for (int k = 0; k < 7; ++k){
    int j = j0 + k; if (j >= NSEL) break;
    const float* row = masked + ((size_t)b * NSEL + j) * 64;
    float d0 = 0.f, d1 = 0.f;
    for (int a = 0; a < 64; ++a){
      float v = row[a];
      float u = v - c0[a]; d0 = fmaf(u, u, d0);
      float w = v - c1[a]; d1 = fmaf(w, w, d1);
    }
    int lab = (d1 < d0) ? 1 : 0;    // argmin tie -> cluster 0
    bits |= (unsigned)lab << k; n1 += lab; n0 += 1 - lab;
  }
  s0[t] = n0; s1[t] = n1; __syncthreads();
  if (t == 0){
    unsigned a = 0, e = 0;
    for (int i = 0; i < 1024; ++i){ unsigned x = s0[i], y = s1[i]; s0[i] = a; s1[i] = e; a += x; e += y; }
    cnt[b] = a; cnt[8 + b] = e;
  }
  __syncthreads();
  unsigned g0 = s0[t], g1 = s1[t];
  for (int k = 0; k < 7; ++k){
    int j = j0 + k; if (j >= NSEL) break;
    if ((bits >> k) & 1u) list1[(size_t)b * NSEL + g1++] = (unsigned)j;
    else                  list0[(size_t)b * NSEL + g0++] = (unsigned)j;
  }
}

__global__ void k_ms(unsigned* __restrict__ cnt){
  unsigned m0 = 0, m1 = 0;
  for (int b = 0; b < 8; ++b){
    m0 = cnt[b]     > m0 ? cnt[b]     : m0;
    m1 = cnt[8 + b] > m1 ? cnt[8 + b] : m1;
  }
  cnt[16] = m0 < m1 ? m0 : m1;
}

// ===================== decoder L1 loss (wave-per-pair) =====================
__global__ __launch_bounds__(256, 2) void k_loss(const float* __restrict__ masked,
    const unsigned* __restrict__ list0, const unsigned* __restrict__ list1,
    const unsigned* __restrict__ cnt,
    const float* __restrict__ dw1, const float* __restrict__ db1,
    const float* __restrict__ dw2, const float* __restrict__ db2,
    double* __restrict__ partial){
  __shared__ float w1t[64 * 128];   // w1t[c][k] = dw1[k][c]  (bank-conflict-free: stride 128)
  __shared__ float w2t[128 * 64];   // w2t[k][e] = dw2[e][k]
  const int tid = threadIdx.x;
  for (int i = tid; i < 64 * 128; i += 256){ int c = i >> 7, k = i & 127; w1t[i] = dw1[k * 64 + c]; }
  for (int i = tid; i < 128 * 64; i += 256){ int k = i >> 6, e = i & 63;  w2t[i] = dw2[e * 128 + k]; }
  __syncthreads();
  const int wv = tid >> 6, a = tid & 63;
  const float h0b = db1[a], h1b = db1[a + 64], ob = db2[a];
  const unsigned ms = cnt[16];
  const int gw = blockIdx.x * 4 + wv;
  double acc = 0.0;
  for (int it = 0; it < 7; ++it){
    int t = gw + it * (LOSS_BLOCKS * 4);
    if (t >= NTOT) continue;                 // wave-uniform
    int b = t / NSEL, j = t - b * NSEL;
    if ((unsigned)j >= ms) continue;         // wave-uniform
    float x1 = 0.f, x2 = 0.f;
    if ((unsigned)j < cnt[b])     x1 = masked[((size_t)b * NSEL + list0[(size_t)b * NSEL + j]) * 64 + a];
    if ((unsigned)j < cnt[8 + b]) x2 = masked[((size_t)b * NSEL + list1[(size_t)b * NSEL + j]) * 64 + a];
    #pragma unroll
    for (int dir = 0; dir < 2; ++dir){
      float xin  = dir ? x1 : x2;   // decoder input
      float xcmp = dir ? x2 : x1;   // compare target
      float h0 = h0b, h1 = h1b;
      #pragma unroll
      for (int c = 0; c < 64; ++c){
        float xv = __shfl(xin, c);
        h0 = fmaf(w1t[c * 128 + a],      xv, h0);
        h1 = fmaf(w1t[c * 128 + 64 + a], xv, h1);
      }
      h0 = fmaxf(h0, 0.f); h1 = fmaxf(h1, 0.f);
      float o = ob;
      #pragma unroll
      for (int k = 0; k < 64; ++k){
        float hA = __shfl(h0, k);
        float hB = __shfl(h1, k);
        o = fmaf(w2t[k * 64 + a],        hA, o);
        o = fmaf(w2t[(k + 64) * 64 + a], hB, o);
      }
      acc += (double)fabsf(o - xcmp);
    }
  }
  for (int off = 32; off > 0; off >>= 1) acc += __shfl_down(acc, off);
  if (a == 0) partial[blockIdx.x * 4 + wv] = acc;
}

__global__ void k_final(const double* __restrict__ partial, const unsigned* __restrict__ cnt,
                        float* __restrict__ out){
  __shared__ double s[1024];
  int t = threadIdx.x;
  double a = 0.0;
  for (int k = 0; k < 8; ++k) a += partial[t + k * 1024];
  s[t] = a; __syncthreads();
  for (int off = 512; off > 0; off >>= 1){
    if (t < off) s[t] += s[t + off];
    __syncthreads();
  }
  if (t == 0){
    unsigned ms = cnt[16];
    double denom = 512.0 * (double)ms;   // B*ATTR*ms
    out[0] = (float)(ms ? s[0] / denom : 0.0);
  }
}

// ===================== launch =====================
extern "C" void kernel_launch(void* const* d_in, const int* in_sizes, int n_in,
                              void* d_out, int out_size, void* d_ws, size_t ws_size,
                              hipStream_t stream){
  (void)in_sizes; (void)n_in; (void)out_size; (void)ws_size;
  const float* Fe  = (const float*)d_in[0];
  const float* w1  = (const float*)d_in[2];
  const float* b1  = (const float*)d_in[3];
  const float* w2  = (const float*)d_in[4];
  const float* b2  = (const float*)d_in[5];
  const float* dw1 = (const float*)d_in[6];
  const float* db1 = (const float*)d_in[7];
  const float* dw2 = (const float*)d_in[8];
  const float* db2 = (const float*)d_in[9];
  float* out = (float*)d_out;
  char* ws = (char*)d_ws;

  float*              bnd      = (float*)(ws + OFF_BND);
  unsigned*           hist_hi  = (unsigned*)(ws + OFF_HIST_HI);
  unsigned*           hist_lo  = (unsigned*)(ws + OFF_HIST_LO);
  unsigned*           bucketA  = (unsigned*)(ws + OFF_BUCKETA);
  unsigned*           rankinfo = (unsigned*)(ws + OFF_RANKINFO);
  unsigned short*     selpos   = (unsigned short*)(ws + OFF_SELPOS);
  unsigned long long* minb     = (unsigned long long*)(ws + OFF_MIN);
  unsigned*           thr      = (unsigned*)(ws + OFF_THR);
  unsigned*           cnt      = (unsigned*)(ws + OFF_CNT);
  float*              centers  = (float*)(ws + OFF_CENTERS);
  unsigned long long* cand     = (unsigned long long*)(ws + OFF_CAND);
  unsigned*           list0    = (unsigned*)(ws + OFF_LIST0);
  unsigned*           list1    = (unsigned*)(ws + OFF_LIST1);
  double*             partial  = (double*)(ws + OFF_PARTIAL);
  __half*             Xg       = (__half*)(ws + OFF_XG);
  float*              masked   = (float*)(ws + OFF_MASKED);

  k_init<<<dim3((ZERO_WORDS + 255) / 256), dim3(256), 0, stream>>>(ws);
  k_bnd<<<dim3(B_N * (H_N / 4)), dim3(256), 0, stream>>>(Fe, bnd);
  k_hist_hi<<<dim3(B_N * HW_N / 256), dim3(256), 0, stream>>>(bnd, hist_hi);
  k_thresh_hi<<<dim3(B_N), dim3(1024), 0, stream>>>(hist_hi, thr);
  k_hist_lo<<<dim3(B_N * HW_N / 256), dim3(256), 0, stream>>>(bnd, thr, hist_lo);
  k_thresh_lo<<<dim3(B_N), dim3(1024), 0, stream>>>(hist_lo, thr);
  k_compact<<<dim3(B_N), dim3(1024), 0, stream>>>(bnd, thr, selpos);
  k_gather<<<dim3(HW_N / 1024, C_N, B_N), dim3(256), 0, stream>>>(Fe, selpos, Xg);
  k_mlp<<<dim3((NTOT + 63) / 64), dim3(256), 0, stream>>>(Xg, w1, b1, w2, b2, masked);
  k_tf1<<<dim3((NHALF + 255) / 256), dim3(256), 0, stream>>>(bucketA, minb);
  k_tf2<<<dim3((NHALF + 255) / 256), dim3(256), 0, stream>>>(minb);
  k_rank<<<dim3(1), dim3(1024), 0, stream>>>(minb, bucketA, rankinfo);
  k_cand<<<dim3((NHALF + 255) / 256), dim3(256), 0, stream>>>(rankinfo, cand);
  k_pick<<<dim3(1), dim3(256), 0, stream>>>(rankinfo, cand, masked, centers);
  k_labels<<<dim3(B_N), dim3(1024), 0, stream>>>(masked, centers, list0, list1, cnt);
  k_ms<<<dim3(1), dim3(1), 0, stream>>>(cnt);
  k_loss<<<dim3(LOSS_BLOCKS), dim3(256), 0, stream>>>(masked, list0, list1, cnt,
                                                      dw1, db1, dw2, db2, partial);
  k_final<<<dim3(1), dim3(1024), 0, stream>>>(partial, cnt, out);
}

// Round 3
// 1391.623 us; speedup vs baseline: 1.3723x; 1.3723x over previous
//
#include <hip/hip_runtime.h>
#include <hip/hip_fp16.h>
#include <stdint.h>
#include <stddef.h>

// Problem constants
#define B_N   8
#define C_N   256
#define H_N   256
#define W_N   256
#define HW_N  65536
#define NSEL  6554        // int(HW*0.1)+1
#define NTOT  52432       // B*NSEL
#define NHALF 26216       // NTOT/2 (threefry counter halves)
#define LOSS_BLOCKS 512

// ---- workspace layout (bytes) ----
static constexpr size_t OFF_BND      = 0;           // f32[B*HW]            2,097,152
static constexpr size_t OFF_HISTM    = 2097152;     // u32[8][65536] merged 2,097,152
static constexpr size_t OFF_HIST_HI  = 4194304;     // u32[8][8][65536]    16,777,216 (zeroed)
static constexpr size_t OFF_HIST_LO  = 20971520;    // u32[8][65536]        2,097,152 (zeroed)
static constexpr size_t OFF_BUCKETA  = 23068672;    // u32[65536]             262,144 (zeroed)
static constexpr size_t OFF_RANKINFO = 23330816;    // u32[64]                    256 (zeroed)
static constexpr size_t OFF_LAB      = 23331072;    // u8[NTOT] pad            52,480
static constexpr size_t OFF_SELPOS   = 23383552;    // u16[B*HW]            1,048,576 (fill 0xFFFF)
static constexpr size_t OFF_MIN      = 24432128;    // u64[2] pad                 256 (fill 0xFF)
static constexpr size_t OFF_THR      = 24432384;    // u32[32]: hb[8], r[8], Tkey[8], eqneed[8]
static constexpr size_t OFF_CNT      = 24432640;    // u32: cnt0[8], cnt1[8], ms@16
static constexpr size_t OFF_CENTERS  = 24432896;    // f32[128]
static constexpr size_t OFF_CAND     = 24433408;    // u64[2][512]
static constexpr size_t OFF_LIST0    = 24441600;    // u32[NTOT] pad          209,920
static constexpr size_t OFF_LIST1    = 24651520;    // u32[NTOT] pad          209,920
static constexpr size_t OFF_PARTIAL  = 24861440;    // f64[2048]               16,384
static constexpr size_t OFF_XG       = 24877824;    // f16[256*NTOT]       26,845,184
static constexpr size_t OFF_MASKED   = 51723008;    // f32[NTOT*64]        13,422,592 -> end 65,145,600

#define ZERO_WORDS   4784192   // HIST_HI..RANKINFO end
#define SELPOS_WORDS 262144

// ===================== parallel block scan (1024 threads, exclusive) =====================
__device__ __forceinline__ unsigned scan1024(unsigned v, unsigned* swave, int tid){
  unsigned incl = v;
  #pragma unroll
  for (int d = 1; d < 64; d <<= 1){
    unsigned n = __shfl_up(incl, d);
    if ((tid & 63) >= d) incl += n;
  }
  if ((tid & 63) == 63) swave[tid >> 6] = incl;
  __syncthreads();
  if (tid < 16){
    unsigned w = swave[tid];
    #pragma unroll
    for (int d = 1; d < 16; d <<= 1){
      unsigned n = __shfl_up(w, d);
      if (tid >= d) w += n;
    }
    swave[tid] = w;
  }
  __syncthreads();
  unsigned woff = (tid >> 6) ? swave[(tid >> 6) - 1] : 0u;
  return woff + incl - v;
}

// ===================== init =====================
__global__ void k_init(char* ws){
  int i = blockIdx.x * 256 + threadIdx.x;
  if (i < ZERO_WORDS)   ((unsigned*)(ws + OFF_HIST_HI))[i] = 0u;
  if (i < SELPOS_WORDS) ((unsigned*)(ws + OFF_SELPOS))[i]  = 0xFFFFFFFFu;
  if (i < 4)            ((unsigned*)(ws + OFF_MIN))[i]     = 0xFFFFFFFFu;
}

// ===================== boundary map (f64 accumulation) =====================
__global__ __launch_bounds__(256) void k_bnd(const float* __restrict__ Fe, float* __restrict__ bnd){
  const int bid = blockIdx.x;
  const int b  = bid >> 6;
  const int h  = ((bid & 63) << 2) + (threadIdx.x >> 6);
  const int tx = threadIdx.x & 63;
  const int w  = tx << 2;
  const size_t base = (size_t)b * C_N * HW_N + (size_t)h * W_N + w;
  const int hn = (h < H_N - 1) ? (h + 1) : (H_N - 2);   // replicate: gy[255]=|Fe[255]-Fe[254]|
  const ptrdiff_t roff = (ptrdiff_t)(hn - h) * W_N;
  double a0 = 0.0, a1 = 0.0, a2 = 0.0, a3 = 0.0;
  for (int c = 0; c < C_N; ++c){
    const float* p = Fe + base + (size_t)c * HW_N;
    const float4 va = *(const float4*)p;
    const float4 vg = *(const float4*)(p + roff);
    const float nx = __shfl_down(va.x, 1);
    const float gx0 = fabsf(va.y - va.x);
    const float gx1 = fabsf(va.z - va.y);
    const float gx2 = fabsf(va.w - va.z);
    const float gx3 = (tx < 63) ? fabsf(nx - va.w) : gx2;  // replicate gx[255]=gx[254]
    a0 += (double)(gx0 + fabsf(vg.x - va.x));
    a1 += (double)(gx1 + fabsf(vg.y - va.y));
    a2 += (double)(gx2 + fabsf(vg.z - va.z));
    a3 += (double)(gx3 + fabsf(vg.w - va.w));
  }
  float4 o; o.x = (float)a0; o.y = (float)a1; o.z = (float)a2; o.w = (float)a3;
  *(float4*)(bnd + (size_t)b * HW_N + (size_t)h * W_N + w) = o;
}

// ===================== top-NSEL radix select =====================
// 8-way replicated histogram: contention on hot buckets / 8
__global__ void k_hist_hi(const float* __restrict__ bnd, unsigned* __restrict__ hist_hi){
  int i = blockIdx.x * 256 + threadIdx.x;     // grid 2048
  int b = i >> 16;
  unsigned rep = blockIdx.x & 7u;
  unsigned key = __float_as_uint(bnd[i]);     // bnd >= 0 -> uint order == float order
  atomicAdd(&hist_hi[(((size_t)b * 8 + rep) << 16) + (key >> 16)], 1u);
}

__global__ void k_merge(const unsigned* __restrict__ hist_hi, unsigned* __restrict__ histm){
  int i = blockIdx.x * 256 + threadIdx.x;     // grid 2048 -> 524288
  int b = i >> 16, d = i & 0xFFFF;
  const unsigned* hb = hist_hi + ((size_t)b * 8) * 65536;
  unsigned s = 0;
  #pragma unroll
  for (int r = 0; r < 8; ++r) s += hb[(size_t)r * 65536 + d];
  histm[i] = s;
}

__global__ __launch_bounds__(1024) void k_thresh_hi(const unsigned* __restrict__ histm,
                                                    unsigned* __restrict__ thr){
  __shared__ unsigned sv[1024];
  __shared__ unsigned swave[16];
  int b = blockIdx.x, t = threadIdx.x;
  const unsigned* hb = histm + (size_t)b * 65536;
  unsigned sum = 0;
  for (int k = 0; k < 64; k += 4){
    uint4 u = *(const uint4*)(hb + t * 64 + k);
    sum += u.x + u.y + u.z + u.w;
  }
  sv[t] = sum; __syncthreads();
  unsigned v = sv[1023 - t];
  unsigned incl = scan1024(v, swave, t) + v;     // suffix sum at chunk p=1023-t
  if (incl >= NSEL && (incl - v) < NSEL){
    int tc = 1023 - t;
    unsigned c2 = incl - v;
    for (int k = 63; k >= 0; --k){
      unsigned h = hb[tc * 64 + k];
      if (c2 + h >= NSEL){ thr[b] = (unsigned)(tc * 64 + k); thr[8 + b] = NSEL - c2; break; }
      c2 += h;
    }
  }
}

__global__ void k_hist_lo(const float* __restrict__ bnd, const unsigned* __restrict__ thr,
                          unsigned* __restrict__ histlo){
  int i = blockIdx.x * 256 + threadIdx.x;
  int b = i >> 16;
  unsigned key = __float_as_uint(bnd[i]);
  if ((key >> 16) == thr[b]) atomicAdd(&histlo[b * 65536 + (key & 0xFFFFu)], 1u);
}

__global__ __launch_bounds__(1024) void k_thresh_lo(const unsigned* __restrict__ histlo,
                                                    unsigned* __restrict__ thr){
  __shared__ unsigned sv[1024];
  __shared__ unsigned swave[16];
  int b = blockIdx.x, t = threadIdx.x;
  const unsigned* hb = histlo + (size_t)b * 65536;
  unsigned sum = 0;
  for (int k = 0; k < 64; k += 4){
    uint4 u = *(const uint4*)(hb + t * 64 + k);
    sum += u.x + u.y + u.z + u.w;
  }
  sv[t] = sum; __syncthreads();
  unsigned v = sv[1023 - t];
  unsigned target = thr[8 + b];
  unsigned incl = scan1024(v, swave, t) + v;
  if (incl >= target && (incl - v) < target){
    int tc = 1023 - t;
    unsigned c2 = incl - v;
    for (int k = 63; k >= 0; --k){
      unsigned h = hb[tc * 64 + k];
      if (c2 + h >= target){
        thr[16 + b] = (thr[b] << 16) | (unsigned)(tc * 64 + k);  // full 32-bit threshold key
        thr[24 + b] = target - c2;                               // ties to take (index order)
        break;
      }
      c2 += h;
    }
  }
}

// ordered compaction: selpos[b][p] = rank among selected (pixel order), 0xFFFF otherwise
__global__ __launch_bounds__(1024) void k_compact(const float* __restrict__ bnd,
                                                  const unsigned* __restrict__ thr,
                                                  unsigned short* __restrict__ selpos){
  __shared__ unsigned swave[16];
  int b = blockIdx.x, t = threadIdx.x;
  unsigned T = thr[16 + b], need = thr[24 + b];
  const float* bb = bnd + (size_t)b * HW_N;
  int p0 = t * 64;
  unsigned ng = 0, ne = 0;
  for (int k = 0; k < 64; k += 4){
    float4 f = *(const float4*)(bb + p0 + k);
    unsigned k0 = __float_as_uint(f.x), k1 = __float_as_uint(f.y);
    unsigned k2 = __float_as_uint(f.z), k3 = __float_as_uint(f.w);
    ng += (k0 > T) + (k1 > T) + (k2 > T) + (k3 > T);
    ne += (k0 == T) + (k1 == T) + (k2 == T) + (k3 == T);
  }
  unsigned excl = scan1024(ng | (ne << 16), swave, t);
  unsigned g = excl & 0xFFFFu, e = excl >> 16;
  for (int k = 0; k < 64; k += 4){
    float4 f = *(const float4*)(bb + p0 + k);
    unsigned keys[4] = { __float_as_uint(f.x), __float_as_uint(f.y),
                         __float_as_uint(f.z), __float_as_uint(f.w) };
    #pragma unroll
    for (int c = 0; c < 4; ++c){
      int p = p0 + k + c;
      if (keys[c] > T){
        unsigned etk = e < need ? e : need;
        selpos[(size_t)b * HW_N + p] = (unsigned short)(g + etk);
        ++g;
      } else if (keys[c] == T){
        if (e < need) selpos[(size_t)b * HW_N + p] = (unsigned short)(g + e);
        ++e;
      }
    }
  }
}

// ===================== coalesced gather Fe -> Xg[c][t] (fp16) =====================
__global__ void k_gather(const float* __restrict__ Fe, const unsigned short* __restrict__ selpos,
                         __half* __restrict__ Xg){
  const int b = blockIdx.z, c = blockIdx.y;
  const int p = blockIdx.x * 1024 + threadIdx.x * 4;
  const float4 v = *(const float4*)(Fe + ((size_t)(b * C_N + c)) * HW_N + p);
  const ushort4 s = *(const ushort4*)(selpos + (size_t)b * HW_N + p);
  __half* xc = Xg + (size_t)c * NTOT + (size_t)b * NSEL;
  if (s.x != 0xFFFFu) xc[s.x] = __float2half(v.x);
  if (s.y != 0xFFFFu) xc[s.y] = __float2half(v.y);
  if (s.z != 0xFFFFu) xc[s.z] = __float2half(v.z);
  if (s.w != 0xFFFFu) xc[s.w] = __float2half(v.w);
}

// ===================== projection MLP at selected points =====================
__global__ __launch_bounds__(256, 2) void k_mlp(const __half* __restrict__ Xg,
    const float* __restrict__ w1, const float* __restrict__ b1,
    const float* __restrict__ w2, const float* __restrict__ b2,
    float* __restrict__ masked){
  __shared__ float xs[64 * 129];   // x chunk [pt][128], reused as h [pt][128]
  const int t0 = blockIdx.x * 64;
  const int tid = threadIdx.x;
  const int wv = __builtin_amdgcn_readfirstlane(tid >> 6);
  const int pt = tid & 63;
  const int t = t0 + pt;

  float acc[32];
  #pragma unroll
  for (int kk = 0; kk < 32; ++kk) acc[kk] = b1[wv * 32 + kk];

  for (int half = 0; half < 2; ++half){
    for (int it = 0; it < 32; ++it){
      int idx = it * 256 + tid;
      int cl = idx >> 6, ptl = idx & 63;
      int tt = t0 + ptl;
      float v = 0.f;
      if (tt < NTOT) v = __half2float(Xg[(size_t)(half * 128 + cl) * NTOT + tt]);
      xs[ptl * 129 + cl] = v;
    }
    __syncthreads();
    for (int cc = 0; cc < 128; cc += 32){
      float xr[32];
      #pragma unroll
      for (int j = 0; j < 32; ++j) xr[j] = xs[pt * 129 + cc + j];
      #pragma unroll
      for (int kk = 0; kk < 32; ++kk){
        const float* wr = w1 + (size_t)(wv * 32 + kk) * 256 + half * 128 + cc;
        float a = acc[kk];
        #pragma unroll
        for (int j = 0; j < 32; ++j) a = fmaf(wr[j], xr[j], a);
        acc[kk] = a;
      }
    }
    __syncthreads();
  }
  #pragma unroll
  for (int kk = 0; kk < 32; ++kk) xs[pt * 129 + wv * 32 + kk] = fmaxf(acc[kk], 0.f);
  __syncthreads();

  float o[16];
  #pragma unroll
  for (int ee = 0; ee < 16; ++ee) o[ee] = b2[wv * 16 + ee];
  for (int kc = 0; kc < 128; kc += 32){
    float hr[32];
    #pragma unroll
    for (int j = 0; j < 32; ++j) hr[j] = xs[pt * 129 + kc + j];
    #pragma unroll
    for (int ee = 0; ee < 16; ++ee){
      const float* wr = w2 + (size_t)(wv * 16 + ee) * 128 + kc;
      float a = o[ee];
      #pragma unroll
      for (int j = 0; j < 32; ++j) a = fmaf(wr[j], hr[j], a);
      o[ee] = a;
    }
  }
  if (t < NTOT){
    float4* mp = (float4*)(masked + (size_t)t * 64 + wv * 16);
    mp[0] = make_float4(o[0], o[1], o[2], o[3]);
    mp[1] = make_float4(o[4], o[5], o[6], o[7]);
    mp[2] = make_float4(o[8], o[9], o[10], o[11]);
    mp[3] = make_float4(o[12], o[13], o[14], o[15]);
  }
}

// ===================== threefry (jax.random.permutation(key(42), NTOT)[:2]) =====================
__device__ __forceinline__ unsigned rotl32(unsigned x, int d){ return (x << d) | (x >> (32 - d)); }

__device__ __forceinline__ void threefry(unsigned k0, unsigned k1, unsigned& x0, unsigned& x1){
  const unsigned ks2 = k0 ^ k1 ^ 0x1BD11BDAu;
  x0 += k0; x1 += k1;
#define TFR(r) { x0 += x1; x1 = rotl32(x1, r); x1 ^= x0; }
  TFR(13) TFR(15) TFR(26) TFR(6)  x0 += k1;  x1 += ks2 + 1u;
  TFR(17) TFR(29) TFR(16) TFR(24) x0 += ks2; x1 += k0 + 2u;
  TFR(13) TFR(15) TFR(26) TFR(6)  x0 += k0;  x1 += k1 + 3u;
  TFR(17) TFR(29) TFR(16) TFR(24) x0 += k1;  x1 += ks2 + 4u;
  TFR(13) TFR(15) TFR(26) TFR(6)  x0 += ks2; x1 += k0 + 5u;
#undef TFR
}

__device__ __forceinline__ void get_subkeys(unsigned& a0, unsigned& a1, unsigned& b0, unsigned& b1){
  unsigned x0 = 0u, x1 = 2u; threefry(0u, 42u, x0, x1);
  unsigned y0 = 1u, y1 = 3u; threefry(0u, 42u, y0, y1);
  a0 = x1; a1 = y1;
  unsigned p0 = 0u, p1 = 2u; threefry(x0, y0, p0, p1);
  unsigned q0 = 1u, q1 = 3u; threefry(x0, y0, q0, q1);
  b0 = p1; b1 = q1;
}

// round-1 key histogram (hi16, spread) + round-2 stable argmin (wave-reduced: 1 atomic/wave)
__global__ void k_tf1(unsigned* __restrict__ bucketA, unsigned long long* __restrict__ minb){
  int q = blockIdx.x * 256 + threadIdx.x;
  bool valid = (q < NHALF);
  unsigned a0, a1, b0, b1; get_subkeys(a0, a1, b0, b1);
  unsigned long long m = ~0ull;
  if (valid){
    unsigned xa0 = (unsigned)q, xa1 = (unsigned)(q + NHALF); threefry(a0, a1, xa0, xa1);
    atomicAdd(&bucketA[xa0 >> 16], 1u);
    atomicAdd(&bucketA[xa1 >> 16], 1u);
    unsigned xb0 = (unsigned)q, xb1 = (unsigned)(q + NHALF); threefry(b0, b1, xb0, xb1);
    unsigned long long p0 = (((unsigned long long)xb0) << 32) | (unsigned)q;
    unsigned long long p1 = (((unsigned long long)xb1) << 32) | (unsigned)(q + NHALF);
    m = p0 < p1 ? p0 : p1;
  }
  #pragma unroll
  for (int off = 32; off > 0; off >>= 1){
    unsigned long long o = __shfl_down(m, off);
    if (o < m) m = o;
  }
  if ((threadIdx.x & 63) == 0 && m != ~0ull) atomicMin(&minb[0], m);
}

__global__ void k_tf2(unsigned long long* __restrict__ minb){
  int q = blockIdx.x * 256 + threadIdx.x;
  bool valid = (q < NHALF);
  unsigned a0, a1, b0, b1; get_subkeys(a0, a1, b0, b1);
  unsigned long long m = ~0ull;
  if (valid){
    unsigned xb0 = (unsigned)q, xb1 = (unsigned)(q + NHALF); threefry(b0, b1, xb0, xb1);
    unsigned j0 = (unsigned)(minb[0] & 0xFFFFFFFFull);
    unsigned long long p0 = (((unsigned long long)xb0) << 32) | (unsigned)q;
    unsigned long long p1 = (((unsigned long long)xb1) << 32) | (unsigned)(q + NHALF);
    if ((unsigned)q != j0) m = p0;
    if ((unsigned)(q + NHALF) != j0 && p1 < m) m = p1;
  }
  #pragma unroll
  for (int off = 32; off > 0; off >>= 1){
    unsigned long long o = __shfl_down(m, off);
    if (o < m) m = o;
  }
  if ((threadIdx.x & 63) == 0 && m != ~0ull) atomicMin(&minb[1], m);
}

__global__ __launch_bounds__(1024) void k_rank(const unsigned long long* __restrict__ minb,
                       const unsigned* __restrict__ bucketA, unsigned* __restrict__ rankinfo){
  __shared__ unsigned swave[16];
  int t = threadIdx.x;
  unsigned sum = 0;
  for (int k = 0; k < 64; k += 4){
    uint4 u = *(const uint4*)(bucketA + t * 64 + k);
    sum += u.x + u.y + u.z + u.w;
  }
  unsigned excl = scan1024(sum, swave, t);
  unsigned incl = excl + sum;
  for (int which = 0; which < 2; ++which){
    unsigned target = (unsigned)(minb[which] & 0xFFFFFFFFull);
    if (incl > target && excl <= target){
      unsigned c2 = excl;
      for (int k = 0; k < 64; ++k){
        unsigned v = bucketA[t * 64 + k];
        if (c2 + v > target){
          rankinfo[which * 2 + 0] = (unsigned)(t * 64 + k);
          rankinfo[which * 2 + 1] = target - c2;
          break;
        }
        c2 += v;
      }
    }
  }
}

__global__ void k_cand(unsigned* __restrict__ rankinfo, unsigned long long* __restrict__ cand){
  int q = blockIdx.x * 256 + threadIdx.x;
  if (q >= NHALF) return;
  unsigned a0, a1, b0, b1; get_subkeys(a0, a1, b0, b1);
  unsigned xa0 = (unsigned)q, xa1 = (unsigned)(q + NHALF); threefry(a0, a1, xa0, xa1);
  unsigned keys[2] = { xa0, xa1 };
  unsigned pos[2]  = { (unsigned)q, (unsigned)(q + NHALF) };
  for (int l = 0; l < 2; ++l){
    unsigned long long pk = (((unsigned long long)keys[l]) << 32) | pos[l];
    if ((keys[l] >> 16) == rankinfo[0]){
      unsigned slot = atomicAdd(&rankinfo[4], 1u);
      if (slot < 512) cand[slot] = pk;
    }
    if ((keys[l] >> 16) == rankinfo[2]){
      unsigned slot = atomicAdd(&rankinfo[5], 1u);
      if (slot < 512) cand[512 + slot] = pk;
    }
  }
}

__global__ void k_pick(const unsigned* __restrict__ rankinfo, const unsigned long long* __restrict__ cand,
                       const float* __restrict__ masked, float* __restrict__ centers){
  __shared__ unsigned sel[2];
  int t = threadIdx.x;
  for (int which = 0; which < 2; ++which){
    unsigned n = rankinfo[4 + which]; if (n > 512) n = 512;
    unsigned r = rankinfo[which * 2 + 1];
    const unsigned long long* cd = cand + which * 512;
    if ((unsigned)t < n){
      unsigned long long me = cd[t];
      unsigned rank = 0;
      for (unsigned i = 0; i < n; ++i) rank += (cd[i] < me);
      if (rank == r) sel[which] = (unsigned)(me & 0xFFFFFFFFull);
    }
  }
  __syncthreads();
  if (t < 64){
    centers[t]      = masked[(size_t)sel[0] * 64 + t];
    centers[64 + t] = masked[(size_t)sel[1] * 64 + t];
  }
}

// ===================== labels (wave-per-point, coalesced) =====================
__global__ __launch_bounds__(256) void k_labels(const float* __restrict__ masked,
    const float* __restrict__ centers, unsigned char* __restrict__ lab){
  const int tid = threadIdx.x;
  const int a = tid & 63;
  const int wv = tid >> 6;
  const float c0v = centers[a], c1v = centers[64 + a];
  const int base = blockIdx.x * 16 + wv * 4;     // grid 3277 covers NTOT exactly
  for (int i = 0; i < 4; ++i){
    int t = base + i;
    if (t >= NTOT) break;
    float v = masked[(size_t)t * 64 + a];
    float u0 = v - c0v, u1 = v - c1v;
    float d0 = u0 * u0, d1 = u1 * u1;
    #pragma unroll
    for (int off = 32; off > 0; off >>= 1){
      d0 += __shfl_xor(d0, off);
      d1 += __shfl_xor(d1, off);
    }
    if (a == 0) lab[t] = (d1 < d0) ? (unsigned char)1 : (unsigned char)0;
  }
}

// ordered per-cluster compaction from label bytes
__global__ __launch_bounds__(1024) void k_lists(const unsigned char* __restrict__ lab,
    unsigned* __restrict__ list0, unsigned* __restrict__ list1, unsigned* __restrict__ cnt){
  __shared__ unsigned swave[16];
  int b = blockIdx.x, t = threadIdx.x;
  const unsigned char* lb = lab + (size_t)b * NSEL;
  int j0 = t * 7;
  unsigned n0 = 0, n1 = 0, bits = 0;
  for (int k = 0; k < 7; ++k){
    int j = j0 + k; if (j >= NSEL) break;
    unsigned l = lb[j];
    bits |= l << k; n1 += l; n0 += 1u - l;
  }
  unsigned excl = scan1024(n0 | (n1 << 16), swave, t);
  unsigned g0 = excl & 0xFFFFu, g1 = excl >> 16;
  if (t == 1023){ cnt[b] = g0 + n0; cnt[8 + b] = g1 + n1; }
  for (int k = 0; k < 7; ++k){
    int j = j0 + k; if (j >= NSEL) break;
    if ((bits >> k) & 1u) list1[(size_t)b * NSEL + g1++] = (unsigned)j;
    else                  list0[(size_t)b * NSEL + g0++] = (unsigned)j;
  }
}

__global__ void k_ms(unsigned* __restrict__ cnt){
  unsigned m0 = 0, m1 = 0;
  for (int b = 0; b < 8; ++b){
    m0 = cnt[b]     > m0 ? cnt[b]     : m0;
    m1 = cnt[8 + b] > m1 ? cnt[8 + b] : m1;
  }
  cnt[16] = m0 < m1 ? m0 : m1;
}

// ===================== decoder L1 loss (wave-per-pair) =====================
__global__ __launch_bounds__(256, 2) void k_loss(const float* __restrict__ masked,
    const unsigned* __restrict__ list0, const unsigned* __restrict__ list1,
    const unsigned* __restrict__ cnt,
    const float* __restrict__ dw1, const float* __restrict__ db1,
    const float* __restrict__ dw2, const float* __restrict__ db2,
    double* __restrict__ partial){
  __shared__ float w1t[64 * 129];   // w1t[c*129+k] = dw1[k][c], padded stride
  __shared__ float w2t[128 * 65];   // w2t[k*65+e]  = dw2[e][k], padded stride
  const int tid = threadIdx.x;
  for (int i = tid; i < 8192; i += 256){ int k = i >> 6, c = i & 63;  w1t[c * 129 + k] = dw1[i]; }
  for (int i = tid; i < 8192; i += 256){ int e = i >> 7, k2 = i & 127; w2t[k2 * 65 + e] = dw2[i]; }
  __syncthreads();
  const int wv = tid >> 6, a = tid & 63;
  const float h0b = db1[a], h1b = db1[a + 64], ob = db2[a];
  const unsigned ms = cnt[16];
  const int gw = blockIdx.x * 4 + wv;
  double acc = 0.0;
  for (int it = 0; it < 26; ++it){
    int t = gw + it * (LOSS_BLOCKS * 4);
    if (t >= NTOT) continue;                 // wave-uniform
    int b = t / NSEL, j = t - b * NSEL;
    if ((unsigned)j >= ms) continue;         // wave-uniform
    float x1 = 0.f, x2 = 0.f;
    if ((unsigned)j < cnt[b])     x1 = masked[((size_t)b * NSEL + list0[(size_t)b * NSEL + j]) * 64 + a];
    if ((unsigned)j < cnt[8 + b]) x2 = masked[((size_t)b * NSEL + list1[(size_t)b * NSEL + j]) * 64 + a];
    #pragma unroll
    for (int dir = 0; dir < 2; ++dir){
      float xin  = dir ? x1 : x2;   // decoder input
      float xcmp = dir ? x2 : x1;   // compare target
      float h0 = h0b, h1 = h1b;
      #pragma unroll
      for (int c = 0; c < 64; ++c){
        float xv = __shfl(xin, c);
        h0 = fmaf(w1t[c * 129 + a],      xv, h0);
        h1 = fmaf(w1t[c * 129 + 64 + a], xv, h1);
      }
      h0 = fmaxf(h0, 0.f); h1 = fmaxf(h1, 0.f);
      float o = ob;
      #pragma unroll
      for (int k = 0; k < 64; ++k){
        float hA = __shfl(h0, k);
        float hB = __shfl(h1, k);
        o = fmaf(w2t[k * 65 + a],        hA, o);
        o = fmaf(w2t[(k + 64) * 65 + a], hB, o);
      }
      acc += (double)fabsf(o - xcmp);
    }
  }
  for (int off = 32; off > 0; off >>= 1) acc += __shfl_down(acc, off);
  if (a == 0) partial[blockIdx.x * 4 + wv] = acc;
}

__global__ __launch_bounds__(1024) void k_final(const double* __restrict__ partial,
                        const unsigned* __restrict__ cnt, float* __restrict__ out){
  __shared__ double s[1024];
  int t = threadIdx.x;
  double a = partial[t] + partial[t + 1024];
  s[t] = a; __syncthreads();
  for (int off = 512; off > 0; off >>= 1){
    if (t < off) s[t] += s[t + off];
    __syncthreads();
  }
  if (t == 0){
    unsigned ms = cnt[16];
    double denom = 512.0 * (double)ms;   // B*ATTR*ms
    out[0] = (float)(ms ? s[0] / denom : 0.0);
  }
}

// ===================== launch =====================
extern "C" void kernel_launch(void* const* d_in, const int* in_sizes, int n_in,
                              void* d_out, int out_size, void* d_ws, size_t ws_size,
                              hipStream_t stream){
  (void)in_sizes; (void)n_in; (void)out_size; (void)ws_size;
  const float* Fe  = (const float*)d_in[0];
  const float* w1  = (const float*)d_in[2];
  const float* b1  = (const float*)d_in[3];
  const float* w2  = (const float*)d_in[4];
  const float* b2  = (const float*)d_in[5];
  const float* dw1 = (const float*)d_in[6];
  const float* db1 = (const float*)d_in[7];
  const float* dw2 = (const float*)d_in[8];
  const float* db2 = (const float*)d_in[9];
  float* out = (float*)d_out;
  char* ws = (char*)d_ws;

  float*              bnd      = (float*)(ws + OFF_BND);
  unsigned*           histm    = (unsigned*)(ws + OFF_HISTM);
  unsigned*           hist_hi  = (unsigned*)(ws + OFF_HIST_HI);
  unsigned*           hist_lo  = (unsigned*)(ws + OFF_HIST_LO);
  unsigned*           bucketA  = (unsigned*)(ws + OFF_BUCKETA);
  unsigned*           rankinfo = (unsigned*)(ws + OFF_RANKINFO);
  unsigned char*      lab      = (unsigned char*)(ws + OFF_LAB);
  unsigned short*     selpos   = (unsigned short*)(ws + OFF_SELPOS);
  unsigned long long* minb     = (unsigned long long*)(ws + OFF_MIN);
  unsigned*           thr      = (unsigned*)(ws + OFF_THR);
  unsigned*           cnt      = (unsigned*)(ws + OFF_CNT);
  float*              centers  = (float*)(ws + OFF_CENTERS);
  unsigned long long* cand     = (unsigned long long*)(ws + OFF_CAND);
  unsigned*           list0    = (unsigned*)(ws + OFF_LIST0);
  unsigned*           list1    = (unsigned*)(ws + OFF_LIST1);
  double*             partial  = (double*)(ws + OFF_PARTIAL);
  __half*             Xg       = (__half*)(ws + OFF_XG);
  float*              masked   = (float*)(ws + OFF_MASKED);

  k_init<<<dim3((ZERO_WORDS + 255) / 256), dim3(256), 0, stream>>>(ws);
  k_bnd<<<dim3(B_N * (H_N / 4)), dim3(256), 0, stream>>>(Fe, bnd);
  k_hist_hi<<<dim3(B_N * HW_N / 256), dim3(256), 0, stream>>>(bnd, hist_hi);
  k_merge<<<dim3(B_N * HW_N / 256), dim3(256), 0, stream>>>(hist_hi, histm);
  k_thresh_hi<<<dim3(B_N), dim3(1024), 0, stream>>>(histm, thr);
  k_hist_lo<<<dim3(B_N * HW_N / 256), dim3(256), 0, stream>>>(bnd, thr, hist_lo);
  k_thresh_lo<<<dim3(B_N), dim3(1024), 0, stream>>>(hist_lo, thr);
  k_compact<<<dim3(B_N), dim3(1024), 0, stream>>>(bnd, thr, selpos);
  k_gather<<<dim3(HW_N / 1024, C_N, B_N), dim3(256), 0, stream>>>(Fe, selpos, Xg);
  k_mlp<<<dim3((NTOT + 63) / 64), dim3(256), 0, stream>>>(Xg, w1, b1, w2, b2, masked);
  k_tf1<<<dim3((NHALF + 255) / 256), dim3(256), 0, stream>>>(bucketA, minb);
  k_tf2<<<dim3((NHALF + 255) / 256), dim3(256), 0, stream>>>(minb);
  k_rank<<<dim3(1), dim3(1024), 0, stream>>>(minb, bucketA, rankinfo);
  k_cand<<<dim3((NHALF + 255) / 256), dim3(256), 0, stream>>>(rankinfo, cand);
  k_pick<<<dim3(1), dim3(256), 0, stream>>>(rankinfo, cand, masked, centers);
  k_labels<<<dim3((NTOT + 15) / 16), dim3(256), 0, stream>>>(masked, centers, lab);
  k_lists<<<dim3(B_N), dim3(1024), 0, stream>>>(lab, list0, list1, cnt);
  k_ms<<<dim3(1), dim3(1), 0, stream>>>(cnt);
  k_loss<<<dim3(LOSS_BLOCKS), dim3(256), 0, stream>>>(masked, list0, list1, cnt,
                                                      dw1, db1, dw2, db2, partial);
  k_final<<<dim3(1), dim3(1024), 0, stream>>>(partial, cnt, out);
}